// Round 1
// baseline (159.735 us; speedup 1.0000x reference)
//
#include <hip/hip_runtime.h>
#include <stdint.h>

// MultiheadAttention: B=2 L=2048 DIM=1024 H=16 d=64, scale = DIM^-0.5 = 1/32
// Pipeline: convert(f32->bf16) -> QKV gemm (bf16 mfma) -> flash attn -> O gemm.
// ws layout (ushort elems): xb[4M] wqb[1M] wkb[1M] wvb[1M] wob[1M]
//                           qb[4M] kb[4M] vtb[4M] ab[4M]  = 48MB

typedef __attribute__((ext_vector_type(8))) short short8;
typedef __attribute__((ext_vector_type(4))) float f32x4;

#define MFMA(a, b, c) __builtin_amdgcn_mfma_f32_16x16x32_bf16((a), (b), (c), 0, 0, 0)

__device__ __forceinline__ ushort f2bf(float f) {
  uint32_t u = __builtin_bit_cast(uint32_t, f);
  u += 0x7fffu + ((u >> 16) & 1u);
  return (ushort)(u >> 16);
}

__device__ __forceinline__ void gl_lds16(const void* g, void* l) {
  __builtin_amdgcn_global_load_lds(
      (const __attribute__((address_space(1))) unsigned int*)g,
      (__attribute__((address_space(3))) unsigned int*)l, 16, 0, 0);
}

// ---------------- kernel 0: f32 -> bf16 conversion ----------------
__global__ __launch_bounds__(256) void convert_all(
    const float* __restrict__ x, const float* __restrict__ wq,
    const float* __restrict__ wk, const float* __restrict__ wv,
    const float* __restrict__ wo, ushort* __restrict__ dst) {
  size_t i4 = (size_t)blockIdx.x * 256 + threadIdx.x;  // 2M float4's
  size_t e = i4 * 4;
  const float* src; size_t off;
  if (e < 4194304u)      { src = x;  off = e; }
  else if (e < 5242880u) { src = wq; off = e - 4194304u; }
  else if (e < 6291456u) { src = wk; off = e - 5242880u; }
  else if (e < 7340032u) { src = wv; off = e - 6291456u; }
  else                   { src = wo; off = e - 7340032u; }
  float4 v = *(const float4*)(src + off);
  ushort4 o = { f2bf(v.x), f2bf(v.y), f2bf(v.z), f2bf(v.w) };
  *(ushort4*)(dst + e) = o;
}

// ---------------- kernel 1: QKV projections ----------------
// y[m][n] = sum_k A[m][k] * W[n][k] + bias[n]   (torch Linear, B^T form)
// z=0: Q *= (1/32)*log2(e), store [bh][l][64]
// z=1: K store [bh][l][64]
// z=2: V store transposed [bh][64][l]
__global__ __launch_bounds__(256) void gemm_qkv(
    const ushort* __restrict__ xb,
    const ushort* __restrict__ wqb, const ushort* __restrict__ wkb,
    const ushort* __restrict__ wvb,
    const float* __restrict__ bq_, const float* __restrict__ bk_,
    const float* __restrict__ bv_,
    ushort* __restrict__ qout, ushort* __restrict__ kout,
    ushort* __restrict__ vtout) {
  __shared__ __align__(16) ushort As[128 * 32];
  __shared__ __align__(16) ushort Bs[128 * 32];
  const int z = blockIdx.z;
  const int bn = blockIdx.x, bm = blockIdx.y;
  const int t = threadIdx.x;
  const int w = t >> 6, lane = t & 63;
  const int wr = w >> 1, wc = w & 1;
  const int l15 = lane & 15, l4 = lane >> 4;

  const ushort* wb = (z == 0) ? wqb : (z == 1 ? wkb : wvb);
  const float* bias = (z == 0) ? bq_ : (z == 1 ? bk_ : bv_);

  f32x4 acc[4][4] = {};

  for (int kt = 0; kt < 32; ++kt) {
    __syncthreads();
#pragma unroll
    for (int rr = 0; rr < 2; ++rr) {
      int c = t + rr * 256;
      int row = c >> 2, cin = c & 3;
      gl_lds16(xb + (bm * 128 + row) * 1024 + kt * 32 + cin * 8, (void*)&As[c * 8]);
      gl_lds16(wb + (bn * 128 + row) * 1024 + kt * 32 + cin * 8, (void*)&Bs[c * 8]);
    }
    __syncthreads();
    short8 af[4], bfr[4];
#pragma unroll
    for (int mf = 0; mf < 4; ++mf)
      af[mf] = *(const short8*)&As[(wr * 64 + mf * 16 + l15) * 32 + l4 * 8];
#pragma unroll
    for (int nf = 0; nf < 4; ++nf)
      bfr[nf] = *(const short8*)&Bs[(wc * 64 + nf * 16 + l15) * 32 + l4 * 8];
#pragma unroll
    for (int mf = 0; mf < 4; ++mf)
#pragma unroll
      for (int nf = 0; nf < 4; ++nf)
        acc[mf][nf] = MFMA(af[mf], bfr[nf], acc[mf][nf]);
  }

  const float qsc = 0.045084439f;  // (1/32) * log2(e)
#pragma unroll
  for (int mf = 0; mf < 4; ++mf) {
#pragma unroll
    for (int nf = 0; nf < 4; ++nf) {
      int n = bn * 128 + wc * 64 + nf * 16 + l15;
      int m0 = bm * 128 + wr * 64 + mf * 16 + l4 * 4;
      float b = bias[n];
      float vals[4];
#pragma unroll
      for (int r = 0; r < 4; ++r) vals[r] = acc[mf][nf][r] + b;
      int bb = m0 >> 11, l0 = m0 & 2047;
      int h = n >> 6, d = n & 63;
      int bh = bb * 16 + h;
      if (z == 2) {
        uint32_t p0 = f2bf(vals[0]) | ((uint32_t)f2bf(vals[1]) << 16);
        uint32_t p1 = f2bf(vals[2]) | ((uint32_t)f2bf(vals[3]) << 16);
        *(uint2*)&vtout[(bh * 64 + d) * 2048 + l0] = make_uint2(p0, p1);
      } else if (z == 0) {
#pragma unroll
        for (int r = 0; r < 4; ++r)
          qout[(bh * 2048 + l0 + r) * 64 + d] = f2bf(vals[r] * qsc);
      } else {
#pragma unroll
        for (int r = 0; r < 4; ++r)
          kout[(bh * 2048 + l0 + r) * 64 + d] = f2bf(vals[r]);
      }
    }
  }
}

// ---------------- kernel 2: flash attention ----------------
// Block: (itile of 128 q-rows, bh). 4 waves, each owns 32 q-rows.
// Swapped QK^T: S^T[j][i] = mfma(A=K rows, B=Q rows); online softmax in
// exp2 domain (Q pre-scaled); P^T -> per-wave LDS; O^T[d][i] += V^T . P^T.
__global__ __launch_bounds__(256) void attn(
    const ushort* __restrict__ qb, const ushort* __restrict__ kb,
    const ushort* __restrict__ vtb, ushort* __restrict__ aout) {
  __shared__ __align__(16) ushort Ks[64 * 64];
  __shared__ __align__(16) ushort Vs[64 * 64];
  __shared__ __align__(16) ushort Ps[4][32 * 64];
  const int it = blockIdx.x, bh = blockIdx.y;
  const int t = threadIdx.x, w = t >> 6, lane = t & 63;
  const int l15 = lane & 15, l4 = lane >> 4;
  const int kvbase = bh * 2048 * 64;

  // Q fragments in registers (B-operand: lane holds Q[i=l15][d=(l4)*8+e])
  const int i0w = it * 128 + w * 32;
  short8 qf[2][2];
#pragma unroll
  for (int nf = 0; nf < 2; ++nf)
#pragma unroll
    for (int ks = 0; ks < 2; ++ks)
      qf[nf][ks] = *(const short8*)&qb[kvbase + (i0w + nf * 16 + l15) * 64 + ks * 32 + l4 * 8];

  f32x4 ot[4][2] = {};
  float mrun[2] = { -INFINITY, -INFINITY };
  float lsum[2] = { 0.f, 0.f };

  for (int jt = 0; jt < 32; ++jt) {
    const int j0 = jt * 64;
    __syncthreads();
    // stage K tile [64 j][64 d] and V^T tile [64 d][64 j], XOR-swizzled source
#pragma unroll
    for (int rr = 0; rr < 2; ++rr) {
      int c = t + rr * 256;
      int row = c >> 3, cin = c & 7;
      int scin = cin ^ (row & 7);
      gl_lds16(kb + kvbase + (j0 + row) * 64 + scin * 8, (void*)&Ks[c * 8]);
      gl_lds16(vtb + kvbase + row * 2048 + j0 + scin * 8, (void*)&Vs[c * 8]);
    }
    __syncthreads();

    // S^T = K . Q^T  (m=j 4 frags, n=i 2 frags, k=d 2 steps)
    f32x4 st[4][2] = {};
#pragma unroll
    for (int ks = 0; ks < 2; ++ks)
#pragma unroll
      for (int mf = 0; mf < 4; ++mf) {
        int row = mf * 16 + l15;
        int ck = (ks * 4 + l4) ^ (row & 7);
        short8 ka = *(const short8*)&Ks[row * 64 + ck * 8];
#pragma unroll
        for (int nf = 0; nf < 2; ++nf)
          st[mf][nf] = MFMA(ka, qf[nf][ks], st[mf][nf]);
      }

    // online softmax per i (= l15 of each n-frag); j spread over mf,reg,l4
#pragma unroll
    for (int nf = 0; nf < 2; ++nf) {
      float mnew = mrun[nf];
#pragma unroll
      for (int mf = 0; mf < 4; ++mf)
#pragma unroll
        for (int r = 0; r < 4; ++r) mnew = fmaxf(mnew, st[mf][nf][r]);
      mnew = fmaxf(mnew, __shfl_xor(mnew, 16));
      mnew = fmaxf(mnew, __shfl_xor(mnew, 32));
      float f = exp2f(mrun[nf] - mnew);
      mrun[nf] = mnew;
      float ts = 0.f;
      int i = nf * 16 + l15;
#pragma unroll
      for (int mf = 0; mf < 4; ++mf) {
        float p0 = exp2f(st[mf][nf][0] - mnew);
        float p1 = exp2f(st[mf][nf][1] - mnew);
        float p2 = exp2f(st[mf][nf][2] - mnew);
        float p3 = exp2f(st[mf][nf][3] - mnew);
        ts += (p0 + p1) + (p2 + p3);
        int j = mf * 16 + l4 * 4;
        uint32_t w0 = f2bf(p0) | ((uint32_t)f2bf(p1) << 16);
        uint32_t w1 = f2bf(p2) | ((uint32_t)f2bf(p3) << 16);
        int byteoff = i * 128 + (((j >> 3) ^ (i & 7)) * 16) + (j & 7) * 2;
        *(uint2*)((unsigned char*)&Ps[w][0] + byteoff) = make_uint2(w0, w1);
      }
      ts += __shfl_xor(ts, 16);
      ts += __shfl_xor(ts, 32);
      lsum[nf] = lsum[nf] * f + ts;
#pragma unroll
      for (int mf = 0; mf < 4; ++mf)
#pragma unroll
        for (int r = 0; r < 4; ++r) ot[mf][nf][r] *= f;
    }

    // O^T += V^T . P^T  (m=d 4 frags, n=i 2 frags, k=j 2 steps)
#pragma unroll
    for (int ks = 0; ks < 2; ++ks) {
      short8 pb[2];
#pragma unroll
      for (int nf = 0; nf < 2; ++nf) {
        int i = nf * 16 + l15;
        int ck = (ks * 4 + l4) ^ (i & 7);
        pb[nf] = *(const short8*)((unsigned char*)&Ps[w][0] + i * 128 + ck * 16);
      }
#pragma unroll
      for (int mf = 0; mf < 4; ++mf) {
        int row = mf * 16 + l15;
        int ck = (ks * 4 + l4) ^ (row & 7);
        short8 va = *(const short8*)&Vs[row * 64 + ck * 8];
#pragma unroll
        for (int nf = 0; nf < 2; ++nf)
          ot[mf][nf] = MFMA(va, pb[nf], ot[mf][nf]);
      }
    }
  }

  // epilogue: normalize, store bf16 [b*2048+i][h*64+d]
  const int b = bh >> 4, h = bh & 15;
#pragma unroll
  for (int nf = 0; nf < 2; ++nf) {
    float inv = 1.0f / lsum[nf];
    int i = it * 128 + w * 32 + nf * 16 + l15;
#pragma unroll
    for (int mf = 0; mf < 4; ++mf) {
      int d0 = mf * 16 + l4 * 4;
      uint32_t p0 = f2bf(ot[mf][nf][0] * inv) | ((uint32_t)f2bf(ot[mf][nf][1] * inv) << 16);
      uint32_t p1 = f2bf(ot[mf][nf][2] * inv) | ((uint32_t)f2bf(ot[mf][nf][3] * inv) << 16);
      *(uint2*)&aout[(b * 2048 + i) * 1024 + h * 64 + d0] = make_uint2(p0, p1);
    }
  }
}

// ---------------- kernel 3: output projection (f32 out + bias) ----------------
__global__ __launch_bounds__(256) void gemm_out(
    const ushort* __restrict__ ab, const ushort* __restrict__ wob,
    const float* __restrict__ bo_, float* __restrict__ out) {
  __shared__ __align__(16) ushort As[128 * 32];
  __shared__ __align__(16) ushort Bs[128 * 32];
  const int bn = blockIdx.x, bm = blockIdx.y;
  const int t = threadIdx.x;
  const int w = t >> 6, lane = t & 63;
  const int wr = w >> 1, wc = w & 1;
  const int l15 = lane & 15, l4 = lane >> 4;

  f32x4 acc[4][4] = {};

  for (int kt = 0; kt < 32; ++kt) {
    __syncthreads();
#pragma unroll
    for (int rr = 0; rr < 2; ++rr) {
      int c = t + rr * 256;
      int row = c >> 2, cin = c & 3;
      gl_lds16(ab + (bm * 128 + row) * 1024 + kt * 32 + cin * 8, (void*)&As[c * 8]);
      gl_lds16(wob + (bn * 128 + row) * 1024 + kt * 32 + cin * 8, (void*)&Bs[c * 8]);
    }
    __syncthreads();
    short8 af[4], bfr[4];
#pragma unroll
    for (int mf = 0; mf < 4; ++mf)
      af[mf] = *(const short8*)&As[(wr * 64 + mf * 16 + l15) * 32 + l4 * 8];
#pragma unroll
    for (int nf = 0; nf < 4; ++nf)
      bfr[nf] = *(const short8*)&Bs[(wc * 64 + nf * 16 + l15) * 32 + l4 * 8];
#pragma unroll
    for (int mf = 0; mf < 4; ++mf)
#pragma unroll
      for (int nf = 0; nf < 4; ++nf)
        acc[mf][nf] = MFMA(af[mf], bfr[nf], acc[mf][nf]);
  }

#pragma unroll
  for (int mf = 0; mf < 4; ++mf)
#pragma unroll
    for (int nf = 0; nf < 4; ++nf) {
      int n = bn * 128 + wc * 64 + nf * 16 + l15;
      int m0 = bm * 128 + wr * 64 + mf * 16 + l4 * 4;
      float b = bo_[n];
#pragma unroll
      for (int r = 0; r < 4; ++r)
        out[(size_t)(m0 + r) * 1024 + n] = acc[mf][nf][r] + b;
    }
}

extern "C" void kernel_launch(void* const* d_in, const int* in_sizes, int n_in,
                              void* d_out, int out_size, void* d_ws, size_t ws_size,
                              hipStream_t stream) {
  const float* x  = (const float*)d_in[0];
  const float* wq = (const float*)d_in[1];
  const float* bq = (const float*)d_in[2];
  const float* wk = (const float*)d_in[3];
  const float* bk = (const float*)d_in[4];
  const float* wv = (const float*)d_in[5];
  const float* bv = (const float*)d_in[6];
  const float* wo = (const float*)d_in[7];
  const float* bo = (const float*)d_in[8];

  ushort* ws  = (ushort*)d_ws;
  ushort* xb  = ws;
  ushort* wqb = ws + 4194304;
  ushort* wkb = ws + 5242880;
  ushort* wvb = ws + 6291456;
  ushort* wob = ws + 7340032;
  ushort* qbp = ws + 8388608;
  ushort* kbp = ws + 12582912;
  ushort* vtb = ws + 16777216;
  ushort* ab  = ws + 20971520;

  convert_all<<<8192, 256, 0, stream>>>(x, wq, wk, wv, wo, ws);
  gemm_qkv<<<dim3(8, 32, 3), 256, 0, stream>>>(xb, wqb, wkb, wvb, bq, bk, bv,
                                               qbp, kbp, vtb);
  attn<<<dim3(16, 32), 256, 0, stream>>>(qbp, kbp, vtb, ab);
  gemm_out<<<dim3(8, 32), 256, 0, stream>>>(ab, wob, bo, (float*)d_out);
}

// Round 3
// 150.881 us; speedup vs baseline: 1.0587x; 1.0587x over previous
//
#include <hip/hip_runtime.h>
#include <hip/hip_bf16.h>
#include <stdint.h>

// MultiheadAttention: B=2 L=2048 DIM=1024 H=16 d=64, scale = DIM^-0.5 = 1/32
// Pipeline: convert(f32->bf16) -> QKV gemm (bf16 mfma) -> flash attn -> O gemm.
// ws layout (ushort elems): xb[4M] wqb[1M] wkb[1M] wvb[1M] wob[1M]
//                           qb[4M] kb[4M] vtb[4M] ab[4M]  = 48MB

typedef __attribute__((ext_vector_type(8))) short short8;
typedef __attribute__((ext_vector_type(4))) float f32x4;

#define MFMA(a, b, c) __builtin_amdgcn_mfma_f32_16x16x32_bf16((a), (b), (c), 0, 0, 0)

__device__ __forceinline__ ushort f2bf(float f) {
  uint32_t u = __builtin_bit_cast(uint32_t, f);
  u += 0x7fffu + ((u >> 16) & 1u);
  return (ushort)(u >> 16);
}

// packed f32x2 -> bf16x2 (compiler emits packed cvt; memcpy = free reg move)
__device__ __forceinline__ uint32_t pkbf(float lo, float hi) {
  __hip_bfloat162 h = __float22bfloat162_rn(make_float2(lo, hi));
  uint32_t u;
  __builtin_memcpy(&u, &h, 4);
  return u;
}

__device__ __forceinline__ void gl_lds16(const void* g, void* l) {
  __builtin_amdgcn_global_load_lds(
      (const __attribute__((address_space(1))) unsigned int*)g,
      (__attribute__((address_space(3))) unsigned int*)l, 16, 0, 0);
}

// ---------------- kernel 0: f32 -> bf16 conversion ----------------
__global__ __launch_bounds__(256) void convert_all(
    const float* __restrict__ x, const float* __restrict__ wq,
    const float* __restrict__ wk, const float* __restrict__ wv,
    const float* __restrict__ wo, ushort* __restrict__ dst) {
  size_t i4 = (size_t)blockIdx.x * 256 + threadIdx.x;  // 2M float4's
  size_t e = i4 * 4;
  const float* src; size_t off;
  if (e < 4194304u)      { src = x;  off = e; }
  else if (e < 5242880u) { src = wq; off = e - 4194304u; }
  else if (e < 6291456u) { src = wk; off = e - 5242880u; }
  else if (e < 7340032u) { src = wv; off = e - 6291456u; }
  else                   { src = wo; off = e - 7340032u; }
  float4 v = *(const float4*)(src + off);
  ushort4 o = { f2bf(v.x), f2bf(v.y), f2bf(v.z), f2bf(v.w) };
  *(ushort4*)(dst + e) = o;
}

// ---------------- kernel 1: QKV projections ----------------
// y[m][n] = sum_k A[m][k] * W[n][k] + bias[n]   (torch Linear, B^T form)
// z=0: Q *= (1/32)*log2(e), store [bh][l][64]
// z=1: K store [bh][l][64]
// z=2: V store transposed [bh][64][l]
__global__ __launch_bounds__(256) void gemm_qkv(
    const ushort* __restrict__ xb,
    const ushort* __restrict__ wqb, const ushort* __restrict__ wkb,
    const ushort* __restrict__ wvb,
    const float* __restrict__ bq_, const float* __restrict__ bk_,
    const float* __restrict__ bv_,
    ushort* __restrict__ qout, ushort* __restrict__ kout,
    ushort* __restrict__ vtout) {
  __shared__ __align__(16) ushort As[128 * 32];
  __shared__ __align__(16) ushort Bs[128 * 32];
  const int z = blockIdx.z;
  const int bn = blockIdx.x, bm = blockIdx.y;
  const int t = threadIdx.x;
  const int w = t >> 6, lane = t & 63;
  const int wr = w >> 1, wc = w & 1;
  const int l15 = lane & 15, l4 = lane >> 4;

  const ushort* wb = (z == 0) ? wqb : (z == 1 ? wkb : wvb);
  const float* bias = (z == 0) ? bq_ : (z == 1 ? bk_ : bv_);

  f32x4 acc[4][4] = {};

  for (int kt = 0; kt < 32; ++kt) {
    __syncthreads();
#pragma unroll
    for (int rr = 0; rr < 2; ++rr) {
      int c = t + rr * 256;
      int row = c >> 2, cin = c & 3;
      gl_lds16(xb + (bm * 128 + row) * 1024 + kt * 32 + cin * 8, (void*)&As[c * 8]);
      gl_lds16(wb + (bn * 128 + row) * 1024 + kt * 32 + cin * 8, (void*)&Bs[c * 8]);
    }
    __syncthreads();
    short8 af[4], bfr[4];
#pragma unroll
    for (int mf = 0; mf < 4; ++mf)
      af[mf] = *(const short8*)&As[(wr * 64 + mf * 16 + l15) * 32 + l4 * 8];
#pragma unroll
    for (int nf = 0; nf < 4; ++nf)
      bfr[nf] = *(const short8*)&Bs[(wc * 64 + nf * 16 + l15) * 32 + l4 * 8];
    __builtin_amdgcn_s_setprio(1);
#pragma unroll
    for (int mf = 0; mf < 4; ++mf)
#pragma unroll
      for (int nf = 0; nf < 4; ++nf)
        acc[mf][nf] = MFMA(af[mf], bfr[nf], acc[mf][nf]);
    __builtin_amdgcn_s_setprio(0);
  }

  const float qsc = 0.045084439f;  // (1/32) * log2(e)
#pragma unroll
  for (int mf = 0; mf < 4; ++mf) {
#pragma unroll
    for (int nf = 0; nf < 4; ++nf) {
      int n = bn * 128 + wc * 64 + nf * 16 + l15;
      int m0 = bm * 128 + wr * 64 + mf * 16 + l4 * 4;
      float b = bias[n];
      float vals[4];
#pragma unroll
      for (int r = 0; r < 4; ++r) vals[r] = acc[mf][nf][r] + b;
      int bb = m0 >> 11, l0 = m0 & 2047;
      int h = n >> 6, d = n & 63;
      int bh = bb * 16 + h;
      if (z == 2) {
        *(uint2*)&vtout[(bh * 64 + d) * 2048 + l0] =
            make_uint2(pkbf(vals[0], vals[1]), pkbf(vals[2], vals[3]));
      } else if (z == 0) {
#pragma unroll
        for (int r = 0; r < 4; ++r)
          qout[(bh * 2048 + l0 + r) * 64 + d] = f2bf(vals[r] * qsc);
      } else {
#pragma unroll
        for (int r = 0; r < 4; ++r)
          kout[(bh * 2048 + l0 + r) * 64 + d] = f2bf(vals[r]);
      }
    }
  }
}

// ---------------- kernel 2: flash attention ----------------
// Block: 64 q-rows x bh; 4 waves, each owns 16 q-rows. Grid 1024 = 4 blk/CU.
// XCD decode: each XCD owns 4 bh entirely (KV L2-resident, 2MB/XCD).
// Swapped QK^T: S^T[j][i] = mfma(A=K rows, B=Q rows); online softmax in
// exp2 domain (Q pre-scaled); defer-max THR=8; P^T -> per-wave LDS;
// O^T[d][i] += V^T . P^T.
__global__ __launch_bounds__(256) void attn(
    const ushort* __restrict__ qb, const ushort* __restrict__ kb,
    const ushort* __restrict__ vtb, ushort* __restrict__ aout) {
  __shared__ __align__(16) ushort Ks[64 * 64];
  __shared__ __align__(16) ushort Vs[64 * 64];
  __shared__ __align__(16) ushort Ps[4][16 * 64];
  const int bid = blockIdx.x;
  const int xcd = bid & 7, idx = bid >> 3;
  const int bh = xcd * 4 + (idx >> 5);
  const int it = idx & 31;
  const int t = threadIdx.x, w = t >> 6, lane = t & 63;
  const int l15 = lane & 15, l4 = lane >> 4;
  const int kvbase = bh * 2048 * 64;

  // Q fragments in registers (B-operand: lane holds Q[i=l15][d=ks*32+l4*8+e])
  const int i0w = it * 64 + w * 16;
  short8 qf[2];
#pragma unroll
  for (int ks = 0; ks < 2; ++ks)
    qf[ks] = *(const short8*)&qb[kvbase + (i0w + l15) * 64 + ks * 32 + l4 * 8];

  f32x4 ot[4] = {};
  float mrun = -INFINITY;
  float lsum = 0.f;

  unsigned char* const psw = (unsigned char*)&Ps[w][0];

  for (int jt = 0; jt < 32; ++jt) {
    const int j0 = jt * 64;
    __syncthreads();
    // stage K tile [64 j][64 d] and V^T tile [64 d][64 j], XOR-swizzled source
#pragma unroll
    for (int rr = 0; rr < 2; ++rr) {
      int c = t + rr * 256;
      int row = c >> 3, cin = c & 7;
      int scin = cin ^ (row & 7);
      gl_lds16(kb + kvbase + (j0 + row) * 64 + scin * 8, (void*)&Ks[c * 8]);
      gl_lds16(vtb + kvbase + row * 2048 + j0 + scin * 8, (void*)&Vs[c * 8]);
    }
    __syncthreads();

    // S^T = K . Q^T  (m=j 4 frags, k=d 2 steps); C: col=i(l15), row=j(l4*4+r)
    f32x4 st[4] = {};
#pragma unroll
    for (int ks = 0; ks < 2; ++ks) {
#pragma unroll
      for (int mf = 0; mf < 4; ++mf) {
        int row = mf * 16 + l15;
        int ck = (ks * 4 + l4) ^ (row & 7);
        short8 ka = *(const short8*)&Ks[row * 64 + ck * 8];
        __builtin_amdgcn_s_setprio(1);
        st[mf] = MFMA(ka, qf[ks], st[mf]);
        __builtin_amdgcn_s_setprio(0);
      }
    }

    // row-max over j (mf, r, then l4 copies via shfl)
    float tm0 = fmaxf(fmaxf(st[0][0], st[0][1]), fmaxf(st[0][2], st[0][3]));
    float tm1 = fmaxf(fmaxf(st[1][0], st[1][1]), fmaxf(st[1][2], st[1][3]));
    float tm2 = fmaxf(fmaxf(st[2][0], st[2][1]), fmaxf(st[2][2], st[2][3]));
    float tm3 = fmaxf(fmaxf(st[3][0], st[3][1]), fmaxf(st[3][2], st[3][3]));
    float tmax = fmaxf(fmaxf(tm0, tm1), fmaxf(tm2, tm3));
    tmax = fmaxf(tmax, __shfl_xor(tmax, 16));
    tmax = fmaxf(tmax, __shfl_xor(tmax, 32));

    // defer-max: skip rescale while tile max within 2^8 of running max
    if (!__all(tmax <= mrun + 8.f)) {
      float mnew = fmaxf(mrun, tmax);
      float f = exp2f(mrun - mnew);
      lsum *= f;
#pragma unroll
      for (int mf = 0; mf < 4; ++mf)
#pragma unroll
        for (int r = 0; r < 4; ++r) ot[mf][r] *= f;
      mrun = mnew;
    }

    float ts = 0.f;
    const int i = l15;
#pragma unroll
    for (int mf = 0; mf < 4; ++mf) {
      float p0 = exp2f(st[mf][0] - mrun);
      float p1 = exp2f(st[mf][1] - mrun);
      float p2 = exp2f(st[mf][2] - mrun);
      float p3 = exp2f(st[mf][3] - mrun);
      ts += (p0 + p1) + (p2 + p3);
      int j = mf * 16 + l4 * 4;
      int byteoff = i * 128 + (((j >> 3) ^ (i & 7)) * 16) + (j & 7) * 2;
      *(uint2*)(psw + byteoff) = make_uint2(pkbf(p0, p1), pkbf(p2, p3));
    }
    ts += __shfl_xor(ts, 16);
    ts += __shfl_xor(ts, 32);
    lsum += ts;

    // O^T += V^T . P^T  (m=d 4 frags, k=j 2 steps)
#pragma unroll
    for (int ks = 0; ks < 2; ++ks) {
      int ckp = (ks * 4 + l4) ^ (i & 7);
      short8 pb = *(const short8*)(psw + i * 128 + ckp * 16);
#pragma unroll
      for (int mf = 0; mf < 4; ++mf) {
        int row = mf * 16 + l15;
        int ck = (ks * 4 + l4) ^ (row & 7);
        short8 va = *(const short8*)&Vs[row * 64 + ck * 8];
        __builtin_amdgcn_s_setprio(1);
        ot[mf] = MFMA(va, pb, ot[mf]);
        __builtin_amdgcn_s_setprio(0);
      }
    }
  }

  // epilogue: normalize, store bf16 [b*2048+i][h*64+d]
  const int b = bh >> 4, h = bh & 15;
  float inv = 1.0f / lsum;
  int i = it * 64 + w * 16 + l15;
#pragma unroll
  for (int mf = 0; mf < 4; ++mf) {
    int d0 = mf * 16 + l4 * 4;
    *(uint2*)&aout[(b * 2048 + i) * 1024 + h * 64 + d0] =
        make_uint2(pkbf(ot[mf][0] * inv, ot[mf][1] * inv),
                   pkbf(ot[mf][2] * inv, ot[mf][3] * inv));
  }
}

// ---------------- kernel 3: output projection (f32 out + bias) ----------------
__global__ __launch_bounds__(256) void gemm_out(
    const ushort* __restrict__ ab, const ushort* __restrict__ wob,
    const float* __restrict__ bo_, float* __restrict__ out) {
  __shared__ __align__(16) ushort As[128 * 32];
  __shared__ __align__(16) ushort Bs[128 * 32];
  const int bn = blockIdx.x, bm = blockIdx.y;
  const int t = threadIdx.x;
  const int w = t >> 6, lane = t & 63;
  const int wr = w >> 1, wc = w & 1;
  const int l15 = lane & 15, l4 = lane >> 4;

  f32x4 acc[4][4] = {};

  for (int kt = 0; kt < 32; ++kt) {
    __syncthreads();
#pragma unroll
    for (int rr = 0; rr < 2; ++rr) {
      int c = t + rr * 256;
      int row = c >> 2, cin = c & 3;
      gl_lds16(ab + (bm * 128 + row) * 1024 + kt * 32 + cin * 8, (void*)&As[c * 8]);
      gl_lds16(wob + (bn * 128 + row) * 1024 + kt * 32 + cin * 8, (void*)&Bs[c * 8]);
    }
    __syncthreads();
    short8 af[4], bfr[4];
#pragma unroll
    for (int mf = 0; mf < 4; ++mf)
      af[mf] = *(const short8*)&As[(wr * 64 + mf * 16 + l15) * 32 + l4 * 8];
#pragma unroll
    for (int nf = 0; nf < 4; ++nf)
      bfr[nf] = *(const short8*)&Bs[(wc * 64 + nf * 16 + l15) * 32 + l4 * 8];
    __builtin_amdgcn_s_setprio(1);
#pragma unroll
    for (int mf = 0; mf < 4; ++mf)
#pragma unroll
      for (int nf = 0; nf < 4; ++nf)
        acc[mf][nf] = MFMA(af[mf], bfr[nf], acc[mf][nf]);
    __builtin_amdgcn_s_setprio(0);
  }

#pragma unroll
  for (int mf = 0; mf < 4; ++mf)
#pragma unroll
    for (int nf = 0; nf < 4; ++nf) {
      int n = bn * 128 + wc * 64 + nf * 16 + l15;
      int m0 = bm * 128 + wr * 64 + mf * 16 + l4 * 4;
      float b = bo_[n];
#pragma unroll
      for (int r = 0; r < 4; ++r)
        out[(size_t)(m0 + r) * 1024 + n] = acc[mf][nf][r] + b;
    }
}

extern "C" void kernel_launch(void* const* d_in, const int* in_sizes, int n_in,
                              void* d_out, int out_size, void* d_ws, size_t ws_size,
                              hipStream_t stream) {
  const float* x  = (const float*)d_in[0];
  const float* wq = (const float*)d_in[1];
  const float* bq = (const float*)d_in[2];
  const float* wk = (const float*)d_in[3];
  const float* bk = (const float*)d_in[4];
  const float* wv = (const float*)d_in[5];
  const float* bv = (const float*)d_in[6];
  const float* wo = (const float*)d_in[7];
  const float* bo = (const float*)d_in[8];

  ushort* ws  = (ushort*)d_ws;
  ushort* xb  = ws;
  ushort* wqb = ws + 4194304;
  ushort* wkb = ws + 5242880;
  ushort* wvb = ws + 6291456;
  ushort* wob = ws + 7340032;
  ushort* qbp = ws + 8388608;
  ushort* kbp = ws + 12582912;
  ushort* vtb = ws + 16777216;
  ushort* ab  = ws + 20971520;

  convert_all<<<8192, 256, 0, stream>>>(x, wq, wk, wv, wo, ws);
  gemm_qkv<<<dim3(8, 32, 3), 256, 0, stream>>>(xb, wqb, wkb, wvb, bq, bk, bv,
                                               qbp, kbp, vtb);
  attn<<<1024, 256, 0, stream>>>(qbp, kbp, vtb, ab);
  gemm_out<<<dim3(8, 32), 256, 0, stream>>>(ab, wob, bo, (float*)d_out);
}